// Round 1
// baseline (121.299 us; speedup 1.0000x reference)
//
#include <hip/hip_runtime.h>
#include <math.h>

// SplitBruteForceAntisymmetrize: N=6 (720 perms), D=3, HID=64, BATCH=2048.
// Strategy:
//   c[j][i][h] = sum_d x[j,d] * W1[3i+d, h]   (36 values per lane h, registers)
//   preact[p,h] = b1[h] + sum_i c[perm_p[i]][i][h]
//   psi = sum_h W2[h] * sum_p sign_p * tanh(preact[p,h])      (swapped sums)
//   tanh(z) = 1 - 2/(e^{2z}+1); sum_p sign_p = 0  =>  psi = -2*sum_h W2[h]*(tp-tn)
//   where tp/tn accumulate r = 1/(2^s + 1), s = 2*log2(e)*preact (scale folded
//   into W1/b1 at load). Permutations enumerated via a constexpr-pruned
//   template tree (compile-time register indices, shared partial sums, parity
//   computed at compile time). Signed accumulation in fp64 to stay well under
//   the fp32 reference's cancellation noise.

__device__ __forceinline__ float fexp2(float x) {
#if __has_builtin(__builtin_amdgcn_exp2f)
    return __builtin_amdgcn_exp2f(x);
#else
    return exp2f(x);
#endif
}
__device__ __forceinline__ float frcp(float x) {
#if __has_builtin(__builtin_amdgcn_rcpf)
    return __builtin_amdgcn_rcpf(x);
#else
    return 1.0f / x;
#endif
}

template <int LVL, unsigned USED, int PAR>
struct Node {
    template <int J>
    static __device__ __forceinline__ void step(const float (&c)[6][6], float s,
                                                double& tp, double& tn) {
        if constexpr ((USED & (1u << J)) == 0) {
            // placing particle J at slot LVL adds popcount(USED >> (J+1)) inversions
            constexpr int par2 = PAR ^ (__builtin_popcount(USED >> (J + 1)) & 1);
            Node<LVL + 1, USED | (1u << J), par2>::go(c, s + c[J][LVL], tp, tn);
        }
    }
    static __device__ __forceinline__ void go(const float (&c)[6][6], float s,
                                              double& tp, double& tn) {
        step<0>(c, s, tp, tn);
        step<1>(c, s, tp, tn);
        step<2>(c, s, tp, tn);
        step<3>(c, s, tp, tn);
        step<4>(c, s, tp, tn);
        step<5>(c, s, tp, tn);
    }
};

template <unsigned USED, int PAR>
struct Node<6, USED, PAR> {
    static __device__ __forceinline__ void go(const float (&)[6][6], float s,
                                              double& tp, double& tn) {
        float E = fexp2(s);          // = e^{2*preact}
        float r = frcp(E + 1.0f);    // tanh = 1 - 2r
        if constexpr (PAR == 0) tp += (double)r; else tn += (double)r;
    }
};

__global__ __launch_bounds__(256) void antisym_kernel(
    const float* __restrict__ x1, const float* __restrict__ x2,
    const float* __restrict__ W1a, const float* __restrict__ b1a,
    const float* __restrict__ W2a,
    const float* __restrict__ W1b, const float* __restrict__ b1b,
    const float* __restrict__ W2b,
    float* __restrict__ out, int B) {
    __shared__ float lds_log[4];

    const int lane = threadIdx.x & 63;
    const int wave = threadIdx.x >> 6;
    const int b = blockIdx.x * 2 + (wave >> 1);
    const int ch = wave & 1;

    if (b < B) {
        const float* x  = ch ? x2  : x1;
        const float* W1 = ch ? W1b : W1a;
        const float* b1 = ch ? b1b : b1a;
        const float* W2 = ch ? W2b : W2a;

        const float K = 2.8853900817779268f;  // 2*log2(e)

        float w1c[18];
#pragma unroll
        for (int r = 0; r < 18; ++r) w1c[r] = W1[r * 64 + lane] * K;
        const float b1s = b1[lane] * K;
        const float w2v = W2[lane];

        float xv[18];
        const float* xb = x + b * 18;
#pragma unroll
        for (int r = 0; r < 18; ++r) xv[r] = xb[r];

        float c[6][6];
#pragma unroll
        for (int j = 0; j < 6; ++j)
#pragma unroll
            for (int i = 0; i < 6; ++i)
                c[j][i] = xv[j * 3 + 0] * w1c[i * 3 + 0] +
                          xv[j * 3 + 1] * w1c[i * 3 + 1] +
                          xv[j * 3 + 2] * w1c[i * 3 + 2];

        double tp = 0.0, tn = 0.0;
        Node<0, 0u, 0>::go(c, b1s, tp, tn);

        double v = (double)w2v * (tp - tn) * -2.0;  // this lane's psi share
#pragma unroll
        for (int off = 32; off > 0; off >>= 1) v += __shfl_xor(v, off, 64);

        if (lane == 0) lds_log[wave] = (float)log(fabs(v));
    }
    __syncthreads();
    if (threadIdx.x < 2) {
        int bb = blockIdx.x * 2 + threadIdx.x;
        if (bb < B)
            out[bb] = lds_log[threadIdx.x * 2] + lds_log[threadIdx.x * 2 + 1];
    }
}

extern "C" void kernel_launch(void* const* d_in, const int* in_sizes, int n_in,
                              void* d_out, int out_size, void* d_ws, size_t ws_size,
                              hipStream_t stream) {
    const float* x1  = (const float*)d_in[0];
    const float* x2  = (const float*)d_in[1];
    const float* W1a = (const float*)d_in[2];
    const float* b1a = (const float*)d_in[3];
    const float* W2a = (const float*)d_in[4];
    // d_in[5] = b2a: contributes b2 * sum(signs) = 0, mathematically exact
    const float* W1b = (const float*)d_in[6];
    const float* b1b = (const float*)d_in[7];
    const float* W2b = (const float*)d_in[8];
    // d_in[9] = b2b: same

    const int B = in_sizes[0] / 18;  // (B, 6, 3) flattened
    float* out = (float*)d_out;

    dim3 grid((B + 1) / 2), block(256);
    hipLaunchKernelGGL(antisym_kernel, grid, block, 0, stream,
                       x1, x2, W1a, b1a, W2a, W1b, b1b, W2b, out, B);
}

// Round 3
// 100.452 us; speedup vs baseline: 1.2075x; 1.2075x over previous
//
#include <hip/hip_runtime.h>
#include <math.h>

// SplitBruteForceAntisymmetrize: N=6 (720 perms), D=3, HID=64, BATCH=2048.
// Multiplicative reformulation:
//   preact'(p) = K*(x_perm . W1col_h + b1_h), K = 2*log2(e)
//   tanh(z) = 1 - 2/(2^{preact'} + 1)
//   2^{preact'} = prod_i F[perm(i)][i],  F[j][i] = exp2(K*c[j][i]) (b1 in col 0)
//   => only 36 exp2 per wave; DFS prefix PRODUCT replaces prefix sum.
// Transposition pairing (slots 4,5): each L4 prefix with free {a,b} contributes
//   sign * (r_a - r_b) = sign * (E_b - E_a) / ((E_a+1)(E_b+1))   -- 1 rcp/pair.
// Signed accumulation per pair in fp64 (R2 lesson: S = sum(+-r) ~ 1e-5 while
// r ~ 0.5 -> any fp32 intermediate accumulation at O(1) scale adds ~1e-5 noise
// and fails; fp64 per-pair is exact to ~1e-13).
// __launch_bounds__(256,4): cap 128 VGPRs; live set ~75 (F cols 0..3 = 24,
// t = 30, DFS path + pair temps + acc). Round 1's VGPR_Count=32 proved the
// compiler spills without this.

__device__ __forceinline__ float fexp2(float x) {
#if __has_builtin(__builtin_amdgcn_exp2f)
    return __builtin_amdgcn_exp2f(x);
#else
    return exp2f(x);
#endif
}
__device__ __forceinline__ float frcp(float x) {
#if __has_builtin(__builtin_amdgcn_rcpf)
    return __builtin_amdgcn_rcpf(x);
#else
    return 1.0f / x;
#endif
}

constexpr int lowest_free(unsigned used) {
    for (int j = 0; j < 6; ++j)
        if (!(used & (1u << j))) return j;
    return -1;
}

// DFS over slots; P = running product of F factors; parity at compile time.
template <int LVL, unsigned USED, int PAR>
struct Node {
    template <int J>
    static __device__ __forceinline__ void step(const float (&F)[6][6],
                                                const float (&t)[6][6], float P,
                                                double& acc) {
        if constexpr ((USED & (1u << J)) == 0) {
            // placing particle J next adds popcount(USED>>(J+1)) inversions
            constexpr int par2 = PAR ^ (__builtin_popcount(USED >> (J + 1)) & 1);
            if constexpr (LVL == 0)
                Node<1, (1u << J), par2>::go(F, t, F[J][0], acc);
            else
                Node<LVL + 1, USED | (1u << J), par2>::go(F, t, P * F[J][LVL], acc);
        }
    }
    static __device__ __forceinline__ void go(const float (&F)[6][6],
                                              const float (&t)[6][6], float P,
                                              double& acc) {
        step<0>(F, t, P, acc);
        step<1>(F, t, P, acc);
        step<2>(F, t, P, acc);
        step<3>(F, t, P, acc);
        step<4>(F, t, P, acc);
        step<5>(F, t, P, acc);
    }
};

// Level 4: two free particles a<b form a transposition pair over slots 4,5.
template <unsigned USED, int PAR>
struct Node<4, USED, PAR> {
    static __device__ __forceinline__ void go(const float (&F)[6][6],
                                              const float (&t)[6][6], float P,
                                              double& acc) {
        constexpr int a = lowest_free(USED);
        constexpr int b = lowest_free(USED | (1u << a));
        constexpr int inv_a = __builtin_popcount(USED >> (a + 1));
        constexpr int inv_b = __builtin_popcount((USED | (1u << a)) >> (b + 1));
        constexpr int par_ab = PAR ^ ((inv_a + inv_b) & 1);  // parity of (...,a,b)

        float Ea = P * t[a][b];        // 2^{preact'} for (..., a@4, b@5)
        float Eb = P * t[b][a];        // 2^{preact'} for (..., b@4, a@5)
        float num = Eb - Ea;           // r_a - r_b = (Eb-Ea)/((Ea+1)(Eb+1))
        float den = (Ea + 1.0f) * (Eb + 1.0f);
        float d = num * frcp(den);
        if constexpr (par_ab == 0) acc += (double)d;
        else                       acc -= (double)d;
    }
};

__global__ __launch_bounds__(256, 4) void antisym_kernel(
    const float* __restrict__ x1, const float* __restrict__ x2,
    const float* __restrict__ W1a, const float* __restrict__ b1a,
    const float* __restrict__ W2a,
    const float* __restrict__ W1b, const float* __restrict__ b1b,
    const float* __restrict__ W2b,
    float* __restrict__ out, int B) {
    __shared__ float lds_log[4];

    const int lane = threadIdx.x & 63;
    const int wave = threadIdx.x >> 6;
    const int b = blockIdx.x * 2 + (wave >> 1);
    const int ch = wave & 1;

    if (b < B) {
        const float* x  = ch ? x2  : x1;
        const float* W1 = ch ? W1b : W1a;
        const float* b1 = ch ? b1b : b1a;
        const float* W2 = ch ? W2b : W2a;

        const float K = 2.8853900817779268f;  // 2*log2(e)

        float w1c[18];
#pragma unroll
        for (int r = 0; r < 18; ++r) w1c[r] = W1[r * 64 + lane] * K;
        const float b1s = b1[lane] * K;
        const float w2v = W2[lane];

        float xv[18];
        const float* xb = x + b * 18;
#pragma unroll
        for (int r = 0; r < 18; ++r) xv[r] = xb[r];

        // F[j][i] = 2^{K*(sum_d x[j,d]*W1[3i+d,h]) (+ K*b1 for i==0)}
        float F[6][6];
#pragma unroll
        for (int j = 0; j < 6; ++j)
#pragma unroll
            for (int i = 0; i < 6; ++i) {
                float c = xv[j * 3 + 0] * w1c[i * 3 + 0] +
                          xv[j * 3 + 1] * w1c[i * 3 + 1] +
                          xv[j * 3 + 2] * w1c[i * 3 + 2];
                if (i == 0) c += b1s;
                F[j][i] = fexp2(c);
            }

        // t[a][b] = F[a][4]*F[b][5]  (a placed at slot 4, b at slot 5)
        float t[6][6];
#pragma unroll
        for (int a = 0; a < 6; ++a)
#pragma unroll
            for (int bb = 0; bb < 6; ++bb)
                if (a != bb) t[a][bb] = F[a][4] * F[bb][5];

        double acc = 0.0;  // S = sum_p sign_p * r_p
        Node<0, 0u, 0>::go(F, t, 1.0f, acc);

        // psi_lane = -2 * w2 * S ; b2 contributes b2*sum(signs) = 0 exactly
        double v = (double)w2v * acc * -2.0;
#pragma unroll
        for (int off = 32; off > 0; off >>= 1) v += __shfl_xor(v, off, 64);

        if (lane == 0) lds_log[wave] = logf(fabsf((float)v));
    }
    __syncthreads();
    if (threadIdx.x < 2) {
        int bb = blockIdx.x * 2 + threadIdx.x;
        if (bb < B)
            out[bb] = lds_log[threadIdx.x * 2] + lds_log[threadIdx.x * 2 + 1];
    }
}

extern "C" void kernel_launch(void* const* d_in, const int* in_sizes, int n_in,
                              void* d_out, int out_size, void* d_ws, size_t ws_size,
                              hipStream_t stream) {
    const float* x1  = (const float*)d_in[0];
    const float* x2  = (const float*)d_in[1];
    const float* W1a = (const float*)d_in[2];
    const float* b1a = (const float*)d_in[3];
    const float* W2a = (const float*)d_in[4];
    // d_in[5] = b2a: contributes b2 * sum(signs) = 0 exactly
    const float* W1b = (const float*)d_in[6];
    const float* b1b = (const float*)d_in[7];
    const float* W2b = (const float*)d_in[8];
    // d_in[9] = b2b: same

    const int B = in_sizes[0] / 18;  // (B, 6, 3) flattened
    float* out = (float*)d_out;

    dim3 grid((B + 1) / 2), block(256);
    hipLaunchKernelGGL(antisym_kernel, grid, block, 0, stream,
                       x1, x2, W1a, b1a, W2a, W1b, b1b, W2b, out, B);
}

// Round 4
// 96.743 us; speedup vs baseline: 1.2538x; 1.0383x over previous
//
#include <hip/hip_runtime.h>
#include <math.h>

// SplitBruteForceAntisymmetrize: N=6 (720 perms), D=3, HID=64, BATCH=2048.
// Multiplicative reformulation (R3) + depth-3 triple-combine (R4):
//   F[j][i] = exp2(K*c[j][i]) (K=2log2e, b1 folded into col 0); 2^{preact'} =
//   prod_i F[perm(i)][i]; tanh = 1 - 2/(E+1); sum_p sign_p = 0.
//   Transposition pair {a<b} after prefix P (4 slots placed):
//     d = P*(v-u) / (P^2*u*v + P*(u+v) + 1),  u=F[a][4]F[b][5], v=F[b][4]F[a][5]
//   Per unordered pair precompute w=v-u, s=u+v, q=g[a]g[b] (g[j]=F[j][4]F[j][5]).
//   At each depth-3 node (slots 0-2 placed, 3 free) the 3 children's pairs are
//   merged over a common denominator -> ONE rcp + ONE fp64 add per 6 perms
//   (rcp 360->120, f64 ops 720->240 vs R3).
// Accuracy: signed per-triple results folded in fp64 (R2 lesson: S ~ 1e-5 while
//   terms are O(1) -> fp32 running sums add fatal noise). Triple-combine's
//   common-denominator num has the same absolute error structure (~|d|*eps) as
//   separate fp32 pair d's, so absmax should match R3's 0.25.
// Overflow: den = prod of 6 (E+1) factors; data tail preact ~ 6 sigma ->
//   den <= ~2^105 < 2^128. Safe.
// __launch_bounds__(256,4): cap 128 VGPRs (R1 proved the compiler spills
//   c/F tables to scratch without it; live set here ~95-110).

__device__ __forceinline__ float fexp2(float x) {
#if __has_builtin(__builtin_amdgcn_exp2f)
    return __builtin_amdgcn_exp2f(x);
#else
    return exp2f(x);
#endif
}
__device__ __forceinline__ float frcp(float x) {
#if __has_builtin(__builtin_amdgcn_rcpf)
    return __builtin_amdgcn_rcpf(x);
#else
    return 1.0f / x;
#endif
}

constexpr int lowest_free(unsigned used) {
    for (int j = 0; j < 6; ++j)
        if (!(used & (1u << j))) return j;
    return -1;
}

struct Tbl {
    float F[6][4];   // F[j][i] for slots 0..3 (cols 4,5 live only in w/s/q)
    float w[6][6];   // w[a][b] = v-u   (a<b only)
    float s[6][6];   // s[a][b] = u+v   (a<b only)
    float q[6][6];   // q[a][b] = u*v   (a<b only)
};

// Generic DFS over slots 0..2; P = running product of F factors.
template <int LVL, unsigned USED, int PAR>
struct Node {
    template <int J>
    static __device__ __forceinline__ void step(const Tbl& T, float P,
                                                double& a0, double& a1) {
        if constexpr ((USED & (1u << J)) == 0) {
            constexpr int par2 = PAR ^ (__builtin_popcount(USED >> (J + 1)) & 1);
            if constexpr (LVL == 0)
                Node<1, (1u << J), par2>::go(T, T.F[J][0], a0, a1);
            else
                Node<LVL + 1, USED | (1u << J), par2>::go(T, P * T.F[J][LVL], a0, a1);
        }
    }
    static __device__ __forceinline__ void go(const Tbl& T, float P,
                                              double& a0, double& a1) {
        step<0>(T, P, a0, a1);
        step<1>(T, P, a0, a1);
        step<2>(T, P, a0, a1);
        step<3>(T, P, a0, a1);
        step<4>(T, P, a0, a1);
        step<5>(T, P, a0, a1);
    }
};

// Depth-3 node: slots 0-2 placed; 3 free particles -> 3 children (x@slot3),
// each leaving transposition pair {a<b}; merged over common denominator.
template <unsigned USED, int PAR>
struct Node<3, USED, PAR> {
    // child: x at slot 3, pair (a<b) over slots 4,5. Total parity of base perm
    // (..., x, a, b) computed at compile time.
    template <int X, int A, int B>
    static __device__ __forceinline__ float child_den(const Tbl& T, float P3,
                                                      float& n) {
        float P4 = P3 * T.F[X][3];
        float Q  = P4 * P4;
        n = P4 * T.w[A][B];
        return fmaf(Q, T.q[A][B], fmaf(P4, T.s[A][B], 1.0f));
    }
    template <int X, int A, int B>
    static constexpr int child_sign() {
        constexpr unsigned U4 = USED | (1u << X);
        constexpr int inv_x = __builtin_popcount(USED >> (X + 1));
        constexpr int inv_a = __builtin_popcount(U4 >> (A + 1));
        constexpr int inv_b = __builtin_popcount((U4 | (1u << A)) >> (B + 1));
        return (PAR ^ ((inv_x + inv_a + inv_b) & 1));
    }
    static __device__ __forceinline__ void go(const Tbl& T, float P3,
                                              double& a0, double& a1) {
        constexpr int x0 = lowest_free(USED);
        constexpr int x1 = lowest_free(USED | (1u << x0));
        constexpr int x2 = lowest_free(USED | (1u << x0) | (1u << x1));
        // child x0 -> pair {x1,x2}; x1 -> {x0,x2}; x2 -> {x0,x1} (all sorted)
        constexpr float sg0 = child_sign<x0, x1, x2>() ? -1.0f : 1.0f;
        constexpr float sg1 = child_sign<x1, x0, x2>() ? -1.0f : 1.0f;
        constexpr float sg2 = child_sign<x2, x0, x1>() ? -1.0f : 1.0f;

        float n0, n1, n2;
        float den0 = child_den<x0, x1, x2>(T, P3, n0);
        float den1 = child_den<x1, x0, x2>(T, P3, n1);
        float den2 = child_den<x2, x0, x1>(T, P3, n2);

        float d01 = den0 * den1;
        float den = d01 * den2;
        float t01 = (sg0 * n0) * den1 + (sg1 * n1) * den0;
        float num = t01 * den2 + (sg2 * n2) * d01;
        float r = num * frcp(den);
        if constexpr (USED & 1) a1 += (double)r;
        else                    a0 += (double)r;
    }
};

__global__ __launch_bounds__(256, 4) void antisym_kernel(
    const float* __restrict__ x1, const float* __restrict__ x2,
    const float* __restrict__ W1a, const float* __restrict__ b1a,
    const float* __restrict__ W2a,
    const float* __restrict__ W1b, const float* __restrict__ b1b,
    const float* __restrict__ W2b,
    float* __restrict__ out, int B) {
    __shared__ float lds_log[4];

    const int lane = threadIdx.x & 63;
    const int wave = threadIdx.x >> 6;
    const int b = blockIdx.x * 2 + (wave >> 1);
    const int ch = wave & 1;

    if (b < B) {
        const float* x  = ch ? x2  : x1;
        const float* W1 = ch ? W1b : W1a;
        const float* b1 = ch ? b1b : b1a;
        const float* W2 = ch ? W2b : W2a;

        const float K = 2.8853900817779268f;  // 2*log2(e)

        float w1c[18];
#pragma unroll
        for (int r = 0; r < 18; ++r) w1c[r] = W1[r * 64 + lane] * K;
        const float b1s = b1[lane] * K;
        const float w2v = W2[lane];

        float xv[18];
        const float* xb = x + b * 18;
#pragma unroll
        for (int r = 0; r < 18; ++r) xv[r] = xb[r];

        Tbl T;
        float F4[6], F5[6], g[6];
#pragma unroll
        for (int j = 0; j < 6; ++j) {
#pragma unroll
            for (int i = 0; i < 6; ++i) {
                float c = xv[j * 3 + 0] * w1c[i * 3 + 0] +
                          xv[j * 3 + 1] * w1c[i * 3 + 1] +
                          xv[j * 3 + 2] * w1c[i * 3 + 2];
                if (i == 0) c += b1s;
                float e = fexp2(c);
                if (i < 4) T.F[j][i] = e;
                else if (i == 4) F4[j] = e;
                else F5[j] = e;
            }
            g[j] = F4[j] * F5[j];
        }
#pragma unroll
        for (int a = 0; a < 6; ++a)
#pragma unroll
            for (int bb = a + 1; bb < 6; ++bb) {
                float u = F4[a] * F5[bb];   // (a@4, b@5)
                float v = F4[bb] * F5[a];   // (b@4, a@5)
                T.w[a][bb] = v - u;
                T.s[a][bb] = u + v;
                T.q[a][bb] = g[a] * g[bb];
            }

        double acc0 = 0.0, acc1 = 0.0;  // signed folded; 2 accs break f64 chain
        Node<0, 0u, 0>::go(T, 1.0f, acc0, acc1);

        // psi_lane = -2 * w2 * S ; b2 contributes b2*sum(signs) = 0 exactly
        double v = (double)w2v * (acc0 + acc1) * -2.0;
#pragma unroll
        for (int off = 32; off > 0; off >>= 1) v += __shfl_xor(v, off, 64);

        if (lane == 0) lds_log[wave] = logf(fabsf((float)v));
    }
    __syncthreads();
    if (threadIdx.x < 2) {
        int bb = blockIdx.x * 2 + threadIdx.x;
        if (bb < B)
            out[bb] = lds_log[threadIdx.x * 2] + lds_log[threadIdx.x * 2 + 1];
    }
}

extern "C" void kernel_launch(void* const* d_in, const int* in_sizes, int n_in,
                              void* d_out, int out_size, void* d_ws, size_t ws_size,
                              hipStream_t stream) {
    const float* x1  = (const float*)d_in[0];
    const float* x2  = (const float*)d_in[1];
    const float* W1a = (const float*)d_in[2];
    const float* b1a = (const float*)d_in[3];
    const float* W2a = (const float*)d_in[4];
    // d_in[5] = b2a: contributes b2 * sum(signs) = 0 exactly
    const float* W1b = (const float*)d_in[6];
    const float* b1b = (const float*)d_in[7];
    const float* W2b = (const float*)d_in[8];
    // d_in[9] = b2b: same

    const int B = in_sizes[0] / 18;  // (B, 6, 3) flattened
    float* out = (float*)d_out;

    dim3 grid((B + 1) / 2), block(256);
    hipLaunchKernelGGL(antisym_kernel, grid, block, 0, stream,
                       x1, x2, W1a, b1a, W2a, W1b, b1b, W2b, out, B);
}

// Round 5
// 94.872 us; speedup vs baseline: 1.2786x; 1.0197x over previous
//
#include <hip/hip_runtime.h>
#include <math.h>

// SplitBruteForceAntisymmetrize: N=6 (720 perms), D=3, HID=64, BATCH=2048.
// Multiplicative reformulation (R3) + depth-3 triple-combine (R4):
//   F[j][i] = exp2(K*c[j][i]) (K=2log2e, b1 folded into col 0); 2^{preact'} =
//   prod_i F[perm(i)][i]; tanh = 1 - 2/(E+1); sum_p sign_p = 0.
//   Transposition pair {a<b} after prefix P (4 slots placed):
//     d = P*(v-u) / (P^2*u*v + P*(u+v) + 1),  u=F[a][4]F[b][5], v=F[b][4]F[a][5]
//   Per unordered pair precompute w=v-u, s=u+v, q=g[a]g[b] (g[j]=F[j][4]F[j][5]).
//   At each depth-3 node (slots 0-2 placed, 3 free) the 3 children's pairs are
//   merged over a common denominator -> ONE rcp + ONE fp64 add per 6 perms.
// Accuracy: signed per-triple results folded in fp64 (R2 lesson: S ~ 1e-5 while
//   terms are O(1) -> fp32 running sums add fatal noise). R4 measured 0.1875.
// R5 change (single variable): __launch_bounds__(256,4) -> (256,3).
//   VGPR cap 128 -> 170. Steady-state live set ~110 (F 24 + w/s/q 45 + temps)
//   but scheduler peak can exceed 128 -> spills of table entries re-read
//   8-24x each across the 120-node tree = suspected 2x tax (R1's VGPR=32
//   proved this compiler spills this kernel shape aggressively). Occupancy
//   3 waves/SIMD (12/CU), tail block ~ +8% — net win if spill theory holds.
// Overflow: den = prod of 6 (E+1)-like factors <= ~2^93 at data tails < 2^127.

__device__ __forceinline__ float fexp2(float x) {
#if __has_builtin(__builtin_amdgcn_exp2f)
    return __builtin_amdgcn_exp2f(x);
#else
    return exp2f(x);
#endif
}
__device__ __forceinline__ float frcp(float x) {
#if __has_builtin(__builtin_amdgcn_rcpf)
    return __builtin_amdgcn_rcpf(x);
#else
    return 1.0f / x;
#endif
}

constexpr int lowest_free(unsigned used) {
    for (int j = 0; j < 6; ++j)
        if (!(used & (1u << j))) return j;
    return -1;
}

struct Tbl {
    float F[6][4];   // F[j][i] for slots 0..3 (cols 4,5 live only in w/s/q)
    float w[6][6];   // w[a][b] = v-u   (a<b only)
    float s[6][6];   // s[a][b] = u+v   (a<b only)
    float q[6][6];   // q[a][b] = u*v   (a<b only)
};

// Generic DFS over slots 0..2; P = running product of F factors.
template <int LVL, unsigned USED, int PAR>
struct Node {
    template <int J>
    static __device__ __forceinline__ void step(const Tbl& T, float P,
                                                double& a0, double& a1) {
        if constexpr ((USED & (1u << J)) == 0) {
            constexpr int par2 = PAR ^ (__builtin_popcount(USED >> (J + 1)) & 1);
            if constexpr (LVL == 0)
                Node<1, (1u << J), par2>::go(T, T.F[J][0], a0, a1);
            else
                Node<LVL + 1, USED | (1u << J), par2>::go(T, P * T.F[J][LVL], a0, a1);
        }
    }
    static __device__ __forceinline__ void go(const Tbl& T, float P,
                                              double& a0, double& a1) {
        step<0>(T, P, a0, a1);
        step<1>(T, P, a0, a1);
        step<2>(T, P, a0, a1);
        step<3>(T, P, a0, a1);
        step<4>(T, P, a0, a1);
        step<5>(T, P, a0, a1);
    }
};

// Depth-3 node: slots 0-2 placed; 3 free particles -> 3 children (x@slot3),
// each leaving transposition pair {a<b}; merged over common denominator.
template <unsigned USED, int PAR>
struct Node<3, USED, PAR> {
    template <int X, int A, int B>
    static __device__ __forceinline__ float child_den(const Tbl& T, float P3,
                                                      float& n) {
        float P4 = P3 * T.F[X][3];
        float Q  = P4 * P4;
        n = P4 * T.w[A][B];
        return fmaf(Q, T.q[A][B], fmaf(P4, T.s[A][B], 1.0f));
    }
    template <int X, int A, int B>
    static constexpr int child_sign() {
        constexpr unsigned U4 = USED | (1u << X);
        constexpr int inv_x = __builtin_popcount(USED >> (X + 1));
        constexpr int inv_a = __builtin_popcount(U4 >> (A + 1));
        constexpr int inv_b = __builtin_popcount((U4 | (1u << A)) >> (B + 1));
        return (PAR ^ ((inv_x + inv_a + inv_b) & 1));
    }
    static __device__ __forceinline__ void go(const Tbl& T, float P3,
                                              double& a0, double& a1) {
        constexpr int x0 = lowest_free(USED);
        constexpr int x1 = lowest_free(USED | (1u << x0));
        constexpr int x2 = lowest_free(USED | (1u << x0) | (1u << x1));
        constexpr float sg0 = child_sign<x0, x1, x2>() ? -1.0f : 1.0f;
        constexpr float sg1 = child_sign<x1, x0, x2>() ? -1.0f : 1.0f;
        constexpr float sg2 = child_sign<x2, x0, x1>() ? -1.0f : 1.0f;

        float n0, n1, n2;
        float den0 = child_den<x0, x1, x2>(T, P3, n0);
        float den1 = child_den<x1, x0, x2>(T, P3, n1);
        float den2 = child_den<x2, x0, x1>(T, P3, n2);

        float d01 = den0 * den1;
        float den = d01 * den2;
        float t01 = (sg0 * n0) * den1 + (sg1 * n1) * den0;
        float num = t01 * den2 + (sg2 * n2) * d01;
        float r = num * frcp(den);
        if constexpr (USED & 1) a1 += (double)r;
        else                    a0 += (double)r;
    }
};

__global__ __launch_bounds__(256, 3) void antisym_kernel(
    const float* __restrict__ x1, const float* __restrict__ x2,
    const float* __restrict__ W1a, const float* __restrict__ b1a,
    const float* __restrict__ W2a,
    const float* __restrict__ W1b, const float* __restrict__ b1b,
    const float* __restrict__ W2b,
    float* __restrict__ out, int B) {
    __shared__ float lds_log[4];

    const int lane = threadIdx.x & 63;
    const int wave = threadIdx.x >> 6;
    const int b = blockIdx.x * 2 + (wave >> 1);
    const int ch = wave & 1;

    if (b < B) {
        const float* x  = ch ? x2  : x1;
        const float* W1 = ch ? W1b : W1a;
        const float* b1 = ch ? b1b : b1a;
        const float* W2 = ch ? W2b : W2a;

        const float K = 2.8853900817779268f;  // 2*log2(e)

        float w1c[18];
#pragma unroll
        for (int r = 0; r < 18; ++r) w1c[r] = W1[r * 64 + lane] * K;
        const float b1s = b1[lane] * K;
        const float w2v = W2[lane];

        float xv[18];
        const float* xb = x + b * 18;
#pragma unroll
        for (int r = 0; r < 18; ++r) xv[r] = xb[r];

        Tbl T;
        float F4[6], F5[6], g[6];
#pragma unroll
        for (int j = 0; j < 6; ++j) {
#pragma unroll
            for (int i = 0; i < 6; ++i) {
                float c = xv[j * 3 + 0] * w1c[i * 3 + 0] +
                          xv[j * 3 + 1] * w1c[i * 3 + 1] +
                          xv[j * 3 + 2] * w1c[i * 3 + 2];
                if (i == 0) c += b1s;
                float e = fexp2(c);
                if (i < 4) T.F[j][i] = e;
                else if (i == 4) F4[j] = e;
                else F5[j] = e;
            }
            g[j] = F4[j] * F5[j];
        }
#pragma unroll
        for (int a = 0; a < 6; ++a)
#pragma unroll
            for (int bb = a + 1; bb < 6; ++bb) {
                float u = F4[a] * F5[bb];   // (a@4, b@5)
                float v = F4[bb] * F5[a];   // (b@4, a@5)
                T.w[a][bb] = v - u;
                T.s[a][bb] = u + v;
                T.q[a][bb] = g[a] * g[bb];
            }

        double acc0 = 0.0, acc1 = 0.0;  // signed folded; 2 accs break f64 chain
        Node<0, 0u, 0>::go(T, 1.0f, acc0, acc1);

        // psi_lane = -2 * w2 * S ; b2 contributes b2*sum(signs) = 0 exactly
        double v = (double)w2v * (acc0 + acc1) * -2.0;
#pragma unroll
        for (int off = 32; off > 0; off >>= 1) v += __shfl_xor(v, off, 64);

        if (lane == 0) lds_log[wave] = logf(fabsf((float)v));
    }
    __syncthreads();
    if (threadIdx.x < 2) {
        int bb = blockIdx.x * 2 + threadIdx.x;
        if (bb < B)
            out[bb] = lds_log[threadIdx.x * 2] + lds_log[threadIdx.x * 2 + 1];
    }
}

extern "C" void kernel_launch(void* const* d_in, const int* in_sizes, int n_in,
                              void* d_out, int out_size, void* d_ws, size_t ws_size,
                              hipStream_t stream) {
    const float* x1  = (const float*)d_in[0];
    const float* x2  = (const float*)d_in[1];
    const float* W1a = (const float*)d_in[2];
    const float* b1a = (const float*)d_in[3];
    const float* W2a = (const float*)d_in[4];
    // d_in[5] = b2a: contributes b2 * sum(signs) = 0 exactly
    const float* W1b = (const float*)d_in[6];
    const float* b1b = (const float*)d_in[7];
    const float* W2b = (const float*)d_in[8];
    // d_in[9] = b2b: same

    const int B = in_sizes[0] / 18;  // (B, 6, 3) flattened
    float* out = (float*)d_out;

    dim3 grid((B + 1) / 2), block(256);
    hipLaunchKernelGGL(antisym_kernel, grid, block, 0, stream,
                       x1, x2, W1a, b1a, W2a, W1b, b1b, W2b, out, B);
}